// Round 3
// baseline (30766.602 us; speedup 1.0000x reference)
//
#include <hip/hip_runtime.h>
#include <math.h>

#define TT 128

typedef __attribute__((ext_vector_type(8))) short s8v;
typedef __attribute__((ext_vector_type(4))) float f4v;

__device__ __forceinline__ unsigned short f2bf(float f) {
  union { float f; unsigned int u; } v; v.f = f;
  unsigned int u = v.u;
  u += 0x7FFFu + ((u >> 16) & 1u);
  return (unsigned short)(u >> 16);
}
__device__ __forceinline__ float bf2f(unsigned short h) {
  union { unsigned int u; float f; } v; v.u = ((unsigned int)h) << 16;
  return v.f;
}

struct GP {
  const float* A;         // fp32 activation matrix
  const float* A2;        // MODE1 only: tanh(mem) for gate columns
  long long strideA;      // row stride in floats
  const unsigned int* Bp; // packed (hi<<16)|mid  [Ncat, 1024]
  const unsigned short* Bl; // lo plane            [Ncat, 1024]
  const float* b0; const float* b1; const float* b2;
  float* o0; float* o1; float* o2; float* o3;
  const float* rf;
  const float* g1;
  const float* g2;
  float* memf; float* tmemf;
};

// MODES: 0 = x-projections (xk|xv|g1), 1 = QKV+g2 from mem/tanh(mem),
//        2 = Wo+residual, 3 = Wm1+relu, 4 = Wm2+gates -> mem update
template<int MODE>
__global__ __launch_bounds__(256) void gemm_k(GP p) {
  const int bn = blockIdx.x, bm = blockIdx.y;
  const int tid = threadIdx.x;
  const int lane = tid & 63;
  const int wave = tid >> 6;
  const int wm = (wave >> 1) << 5;
  const int wn = (wave & 1) << 5;
  const int rowA0 = bm << 6, colB0 = bn << 6;

  __shared__ __align__(16) unsigned short lAh[64 * 64];
  __shared__ __align__(16) unsigned short lAm[64 * 64];
  __shared__ __align__(16) unsigned short lAl[64 * 64];
  __shared__ __align__(16) unsigned short lBh[64 * 64];
  __shared__ __align__(16) unsigned short lBm[64 * 64];
  __shared__ __align__(16) unsigned short lBl[64 * 64];

  f4v acc[2][2];
#pragma unroll
  for (int i = 0; i < 2; ++i)
#pragma unroll
    for (int j = 0; j < 2; ++j)
#pragma unroll
      for (int r = 0; r < 4; ++r) acc[i][j][r] = 0.f;

  const int sr = tid >> 3;   // 0..31 (stage rows sr and sr+32)
  const int sc = tid & 7;    // 16B chunk 0..7

  const float* A = p.A;
  if (MODE == 1 && colB0 >= 3072) A = p.A2;

  for (int kt = 0; kt < 16; ++kt) {
    const int kcol = (kt << 6) + (sc << 3);
#pragma unroll
    for (int h = 0; h < 2; ++h) {
      const int r = sr + (h << 5);
      // ---- A: fp32 -> (hi, mid, lo) bf16 split ----
      const float4* fp = reinterpret_cast<const float4*>(A + (size_t)(rowA0 + r) * p.strideA + kcol);
      float4 f0 = fp[0], f1 = fp[1];
      float fv[8] = { f0.x, f0.y, f0.z, f0.w, f1.x, f1.y, f1.z, f1.w };
      s8v ah, am, al;
#pragma unroll
      for (int e = 0; e < 8; ++e) {
        float x = fv[e];
        unsigned short hb = f2bf(x);
        float r1 = x - bf2f(hb);
        unsigned short mb = f2bf(r1);
        float r2 = r1 - bf2f(mb);
        unsigned short lb = f2bf(r2);
        ah[e] = (short)hb; am[e] = (short)mb; al[e] = (short)lb;
      }
      const int pos = (r << 6) + ((sc ^ (r & 7)) << 3);
      *reinterpret_cast<s8v*>(&lAh[pos]) = ah;
      *reinterpret_cast<s8v*>(&lAm[pos]) = am;
      *reinterpret_cast<s8v*>(&lAl[pos]) = al;
      // ---- B: packed (hi|mid) + lo plane ----
      const uint4* up = reinterpret_cast<const uint4*>(p.Bp + (size_t)(colB0 + r) * 1024 + kcol);
      uint4 u0 = up[0], u1 = up[1];
      s8v bh, bm_;
      bh[0] = (short)(u0.x >> 16); bm_[0] = (short)(u0.x & 0xFFFFu);
      bh[1] = (short)(u0.y >> 16); bm_[1] = (short)(u0.y & 0xFFFFu);
      bh[2] = (short)(u0.z >> 16); bm_[2] = (short)(u0.z & 0xFFFFu);
      bh[3] = (short)(u0.w >> 16); bm_[3] = (short)(u0.w & 0xFFFFu);
      bh[4] = (short)(u1.x >> 16); bm_[4] = (short)(u1.x & 0xFFFFu);
      bh[5] = (short)(u1.y >> 16); bm_[5] = (short)(u1.y & 0xFFFFu);
      bh[6] = (short)(u1.z >> 16); bm_[6] = (short)(u1.z & 0xFFFFu);
      bh[7] = (short)(u1.w >> 16); bm_[7] = (short)(u1.w & 0xFFFFu);
      s8v bl = *reinterpret_cast<const s8v*>(p.Bl + (size_t)(colB0 + r) * 1024 + kcol);
      *reinterpret_cast<s8v*>(&lBh[pos]) = bh;
      *reinterpret_cast<s8v*>(&lBm[pos]) = bm_;
      *reinterpret_cast<s8v*>(&lBl[pos]) = bl;
    }
    __syncthreads();
#pragma unroll
    for (int ks = 0; ks < 2; ++ks) {
      s8v afh[2], afm[2], afl[2], bfh[2], bfm[2], bfl[2];
#pragma unroll
      for (int i = 0; i < 2; ++i) {
        const int rr = wm + (i << 4) + (lane & 15);
        const int cc = (ks << 2) + (lane >> 4);
        const int pos = (rr << 6) + ((cc ^ (rr & 7)) << 3);
        afh[i] = *reinterpret_cast<const s8v*>(&lAh[pos]);
        afm[i] = *reinterpret_cast<const s8v*>(&lAm[pos]);
        afl[i] = *reinterpret_cast<const s8v*>(&lAl[pos]);
      }
#pragma unroll
      for (int j = 0; j < 2; ++j) {
        const int rr = wn + (j << 4) + (lane & 15);
        const int cc = (ks << 2) + (lane >> 4);
        const int pos = (rr << 6) + ((cc ^ (rr & 7)) << 3);
        bfh[j] = *reinterpret_cast<const s8v*>(&lBh[pos]);
        bfm[j] = *reinterpret_cast<const s8v*>(&lBm[pos]);
        bfl[j] = *reinterpret_cast<const s8v*>(&lBl[pos]);
      }
#pragma unroll
      for (int i = 0; i < 2; ++i)
#pragma unroll
        for (int j = 0; j < 2; ++j) {
          // small-to-large accumulation; drop only lo*lo (~2^-32 rel)
          acc[i][j] = __builtin_amdgcn_mfma_f32_16x16x32_bf16(afl[i], bfm[j], acc[i][j], 0, 0, 0);
          acc[i][j] = __builtin_amdgcn_mfma_f32_16x16x32_bf16(afm[i], bfl[j], acc[i][j], 0, 0, 0);
          acc[i][j] = __builtin_amdgcn_mfma_f32_16x16x32_bf16(afl[i], bfh[j], acc[i][j], 0, 0, 0);
          acc[i][j] = __builtin_amdgcn_mfma_f32_16x16x32_bf16(afh[i], bfl[j], acc[i][j], 0, 0, 0);
          acc[i][j] = __builtin_amdgcn_mfma_f32_16x16x32_bf16(afm[i], bfm[j], acc[i][j], 0, 0, 0);
          acc[i][j] = __builtin_amdgcn_mfma_f32_16x16x32_bf16(afm[i], bfh[j], acc[i][j], 0, 0, 0);
          acc[i][j] = __builtin_amdgcn_mfma_f32_16x16x32_bf16(afh[i], bfm[j], acc[i][j], 0, 0, 0);
          acc[i][j] = __builtin_amdgcn_mfma_f32_16x16x32_bf16(afh[i], bfh[j], acc[i][j], 0, 0, 0);
        }
    }
    __syncthreads();
  }

#pragma unroll
  for (int i = 0; i < 2; ++i) {
#pragma unroll
    for (int j = 0; j < 2; ++j) {
      const int gcol = colB0 + wn + (j << 4) + (lane & 15);
#pragma unroll
      for (int rg = 0; rg < 4; ++rg) {
        const int grow = rowA0 + wm + (i << 4) + ((lane >> 4) << 2) + rg;
        float v = acc[i][j][rg];
        if (MODE == 0) {
          p.o0[(size_t)grow * 4096 + gcol] = v + p.b0[gcol];
        } else if (MODE == 1) {
          if (gcol < 1024)      p.o0[(size_t)grow * 1024 + gcol] = v + p.b0[gcol];
          else if (gcol < 2048) p.o1[(size_t)grow * 1024 + gcol - 1024] = v + p.b1[gcol - 1024];
          else if (gcol < 3072) p.o2[(size_t)grow * 1024 + gcol - 2048] = v + p.b2[gcol - 2048];
          else                  p.o3[(size_t)grow * 2048 + gcol - 3072] = v;
        } else if (MODE == 2) {
          size_t idx = (size_t)grow * 1024 + gcol;
          p.o0[idx] = v + p.b0[gcol] + p.rf[idx];
        } else if (MODE == 3) {
          size_t idx = (size_t)grow * 1024 + gcol;
          float hh = v + p.b0[gcol];
          p.o0[idx] = hh > 0.f ? hh : 0.f;
        } else if (MODE == 4) {
          size_t idx = (size_t)grow * 1024 + gcol;
          float relu = v + p.b0[gcol];
          relu = relu > 0.f ? relu : 0.f;
          double nm = (double)p.rf[idx] + (double)relu;   // next_mlp
          int b = grow >> 3;
          double gi = (double)p.g1[(size_t)b * 4096 + 2048 + gcol] + (double)p.g2[(size_t)grow * 2048 + gcol];
          double gf = (double)p.g1[(size_t)b * 4096 + 3072 + gcol] + (double)p.g2[(size_t)grow * 2048 + 1024 + gcol];
          double ig = 1.0 / (1.0 + exp(-gi));
          double fg = 1.0 / (1.0 + exp(-gf));
          double nxt = ig * tanh(nm) + fg * (double)p.memf[idx];
          p.memf[idx] = (float)nxt;
          p.tmemf[idx] = (float)tanh(nxt);
        }
      }
    }
  }
}

__global__ __launch_bounds__(128) void attn_k(const float* q, const float* km, const float* vm,
                                              const float* xkv, float* attn) {
  const int b = blockIdx.x >> 3;
  const int h = blockIdx.x & 7;
  const int tid = threadIdx.x;
  __shared__ float sq[8][132];
  __shared__ float sk[9][132];
  __shared__ float sv[9][132];
  __shared__ double sc_[8][12];
  __shared__ double sp[8][12];

  for (int i = tid; i < 8 * 128; i += 128) {
    int s = i >> 7, d = i & 127;
    sq[s][d] = q[(size_t)(b * 8 + s) * 1024 + h * 128 + d];
  }
  for (int i = tid; i < 9 * 128; i += 128) {
    int s = i >> 7, d = i & 127;
    float kv, vv;
    if (s < 8) {
      kv = km[(size_t)(b * 8 + s) * 1024 + h * 128 + d];
      vv = vm[(size_t)(b * 8 + s) * 1024 + h * 128 + d];
    } else {
      kv = xkv[(size_t)b * 4096 + h * 128 + d];
      vv = xkv[(size_t)b * 4096 + 1024 + h * 128 + d];
    }
    sk[s][d] = kv; sv[s][d] = vv;
  }
  __syncthreads();
  if (tid < 72) {
    int s = tid / 9, kk = tid % 9;
    double a = 0.0;
    for (int d = 0; d < 128; ++d) a += (double)sq[s][d] * (double)sk[kk][d];
    sc_[s][kk] = a * 0.08838834764831844055;  // 1/sqrt(128)
  }
  __syncthreads();
  if (tid < 8) {
    double m = -1e300;
    for (int kk = 0; kk < 9; ++kk) m = m > sc_[tid][kk] ? m : sc_[tid][kk];
    double sum = 0.0;
    for (int kk = 0; kk < 9; ++kk) { double e = exp(sc_[tid][kk] - m); sp[tid][kk] = e; sum += e; }
    double inv = 1.0 / sum;
    for (int kk = 0; kk < 9; ++kk) sp[tid][kk] *= inv;
  }
  __syncthreads();
  for (int i = tid; i < 8 * 128; i += 128) {
    int s = i >> 7, d = i & 127;
    double a = 0.0;
    for (int kk = 0; kk < 9; ++kk) a += sp[s][kk] * (double)sv[kk][d];
    attn[(size_t)(b * 8 + s) * 1024 + h * 128 + d] = (float)a;
  }
}

// src fp32 [K=1024, N] row-major -> dst_hm packed (hi<<16|mid) [N,1024], dst_lo [N,1024]
__global__ __launch_bounds__(256) void wtp_k(const float* src, unsigned int* dst_hm,
                                             unsigned short* dst_lo, int N) {
  __shared__ float tile[32][33];
  const int bn = blockIdx.x << 5;
  const int bk = blockIdx.y << 5;
  const int tid = threadIdx.x;
  for (int i = tid; i < 1024; i += 256) {
    int r = i >> 5, c = i & 31;
    tile[r][c] = src[(size_t)(bk + r) * N + bn + c];
  }
  __syncthreads();
  for (int i = tid; i < 1024; i += 256) {
    int r = i >> 5, c = i & 31;
    float v = tile[c][r];
    unsigned short hb = f2bf(v);
    float r1 = v - bf2f(hb);
    unsigned short mb = f2bf(r1);
    unsigned short lb = f2bf(r1 - bf2f(mb));
    size_t o = (size_t)(bn + r) * 1024 + bk + c;
    dst_hm[o] = ((unsigned int)hb << 16) | (unsigned int)mb;
    dst_lo[o] = lb;
  }
}

__global__ __launch_bounds__(256) void biasp_k(const float* bk, const float* bv,
                                               const float* bw, const float* bu, float* xb) {
  int i = blockIdx.x * 256 + threadIdx.x;  // 0..4095
  float v;
  if (i < 1024) v = bk[i];
  else if (i < 2048) v = bv[i - 1024];
  else v = bw[i - 2048] + bu[i - 2048];
  xb[i] = v;
}

__global__ __launch_bounds__(256) void init_k(const float* memory, float* memF, float* tmemF) {
  int i = blockIdx.x * 256 + threadIdx.x;
  float v = memory[i];
  memF[i] = v;
  tmemF[i] = (float)tanh((double)v);
}

extern "C" void kernel_launch(void* const* d_in, const int* in_sizes, int n_in,
                              void* d_out, int out_size, void* d_ws, size_t ws_size,
                              hipStream_t stream) {
  const float* inputs = (const float*)d_in[0];
  const float* memory = (const float*)d_in[1];
  const float* Wq = (const float*)d_in[2];  const float* bq = (const float*)d_in[3];
  const float* Wk = (const float*)d_in[4];  const float* bk = (const float*)d_in[5];
  const float* Wv = (const float*)d_in[6];  const float* bv = (const float*)d_in[7];
  const float* Wo = (const float*)d_in[8];  const float* bo = (const float*)d_in[9];
  const float* Wm1 = (const float*)d_in[10]; const float* bm1 = (const float*)d_in[11];
  const float* Wm2 = (const float*)d_in[12]; const float* bm2 = (const float*)d_in[13];
  const float* Ww = (const float*)d_in[14]; const float* bw = (const float*)d_in[15];
  const float* Wu = (const float*)d_in[16]; const float* bu = (const float*)d_in[17];
  (void)in_sizes; (void)n_in; (void)out_size; (void)ws_size;

  char* ws = (char*)d_ws;
  const size_t MB = 1024 * 1024;
  unsigned int*   wc1_hm = (unsigned int*)(ws + 0 * MB);     // [5120,1024] u32: Wq|Wk|Wv|Wu
  unsigned short* wc1_lo = (unsigned short*)(ws + 20 * MB);  // [5120,1024] u16
  unsigned int*   wc0_hm = (unsigned int*)(ws + 30 * MB);    // [4096,1024] u32: Wk|Wv|Ww
  unsigned short* wc0_lo = (unsigned short*)(ws + 46 * MB);  // [4096,1024] u16
  unsigned int*   wo_hm  = (unsigned int*)(ws + 54 * MB);
  unsigned short* wo_lo  = (unsigned short*)(ws + 58 * MB);
  unsigned int*   wm1_hm = (unsigned int*)(ws + 60 * MB);
  unsigned short* wm1_lo = (unsigned short*)(ws + 64 * MB);
  unsigned int*   wm2_hm = (unsigned int*)(ws + 66 * MB);
  unsigned short* wm2_lo = (unsigned short*)(ws + 70 * MB);
  float* xbias = (float*)(ws + 72 * MB);
  float* memF  = (float*)(ws + 73 * MB);
  float* tmemF = (float*)(ws + 75 * MB);
  float* qF    = (float*)(ws + 77 * MB);
  float* kmemF = (float*)(ws + 79 * MB);
  float* vmemF = (float*)(ws + 81 * MB);
  float* g2F   = (float*)(ws + 83 * MB);                     // [512,2048]
  float* attnF = (float*)(ws + 87 * MB);
  float* naF   = (float*)(ws + 89 * MB);
  float* hidF  = (float*)(ws + 91 * MB);
  float* xkvF  = (float*)(ws + 93 * MB);                     // [64,4096]

  wtp_k<<<dim3(32, 32), 256, 0, stream>>>(Wq, wc1_hm, wc1_lo, 1024);
  wtp_k<<<dim3(32, 32), 256, 0, stream>>>(Wk, wc1_hm + (size_t)1024 * 1024, wc1_lo + (size_t)1024 * 1024, 1024);
  wtp_k<<<dim3(32, 32), 256, 0, stream>>>(Wv, wc1_hm + (size_t)2048 * 1024, wc1_lo + (size_t)2048 * 1024, 1024);
  wtp_k<<<dim3(64, 32), 256, 0, stream>>>(Wu, wc1_hm + (size_t)3072 * 1024, wc1_lo + (size_t)3072 * 1024, 2048);
  wtp_k<<<dim3(32, 32), 256, 0, stream>>>(Wk, wc0_hm, wc0_lo, 1024);
  wtp_k<<<dim3(32, 32), 256, 0, stream>>>(Wv, wc0_hm + (size_t)1024 * 1024, wc0_lo + (size_t)1024 * 1024, 1024);
  wtp_k<<<dim3(64, 32), 256, 0, stream>>>(Ww, wc0_hm + (size_t)2048 * 1024, wc0_lo + (size_t)2048 * 1024, 2048);
  wtp_k<<<dim3(32, 32), 256, 0, stream>>>(Wo, wo_hm, wo_lo, 1024);
  wtp_k<<<dim3(32, 32), 256, 0, stream>>>(Wm1, wm1_hm, wm1_lo, 1024);
  wtp_k<<<dim3(32, 32), 256, 0, stream>>>(Wm2, wm2_hm, wm2_lo, 1024);
  biasp_k<<<dim3(16), 256, 0, stream>>>(bk, bv, bw, bu, xbias);
  init_k<<<dim3(512 * 1024 / 256), 256, 0, stream>>>(memory, memF, tmemF);

  for (int t = 0; t < TT; ++t) {
    { // x_t @ [Wk|Wv|Ww] + [bk|bv|bw+bu] -> xkvF [64,4096]
      GP p = {}; p.A = inputs + (size_t)t * 1024; p.strideA = (long long)TT * 1024;
      p.Bp = wc0_hm; p.Bl = wc0_lo; p.b0 = xbias; p.o0 = xkvF;
      gemm_k<0><<<dim3(64, 1), 256, 0, stream>>>(p);
    }
    { // fused Q|K|V|g2 projection from mem / tanh(mem)
      GP p = {}; p.A = memF; p.A2 = tmemF; p.strideA = 1024; p.Bp = wc1_hm; p.Bl = wc1_lo;
      p.b0 = bq; p.b1 = bk; p.b2 = bv;
      p.o0 = qF; p.o1 = kmemF; p.o2 = vmemF; p.o3 = g2F;
      gemm_k<1><<<dim3(80, 8), 256, 0, stream>>>(p);
    }
    attn_k<<<dim3(512), 128, 0, stream>>>(qF, kmemF, vmemF, xkvF, attnF);
    { // attn @ Wo + bo + mem -> next_attn
      GP p = {}; p.A = attnF; p.strideA = 1024; p.Bp = wo_hm; p.Bl = wo_lo;
      p.b0 = bo; p.rf = memF; p.o0 = naF;
      gemm_k<2><<<dim3(16, 8), 256, 0, stream>>>(p);
    }
    { // relu(next_attn @ Wm1 + bm1)
      GP p = {}; p.A = naF; p.strideA = 1024; p.Bp = wm1_hm; p.Bl = wm1_lo;
      p.b0 = bm1; p.o0 = hidF;
      gemm_k<3><<<dim3(16, 8), 256, 0, stream>>>(p);
    }
    { // next_mlp + gates -> next mem
      GP p = {}; p.A = hidF; p.strideA = 1024; p.Bp = wm2_hm; p.Bl = wm2_lo;
      p.b0 = bm2; p.rf = naF;
      p.g1 = xkvF; p.g2 = g2F; p.memf = memF; p.tmemf = tmemF;
      gemm_k<4><<<dim3(16, 8), 256, 0, stream>>>(p);
    }
  }

  hipMemcpyAsync(d_out, memF, (size_t)512 * 1024 * 4, hipMemcpyDeviceToDevice, stream);
}

// Round 5
// 25813.382 us; speedup vs baseline: 1.1919x; 1.1919x over previous
//
#include <hip/hip_runtime.h>
#include <math.h>

#define TT 128

typedef __attribute__((ext_vector_type(8))) short s8v;
typedef __attribute__((ext_vector_type(4))) float f4v;

__device__ __forceinline__ unsigned short f2bf(float f) {
  union { float f; unsigned int u; } v; v.f = f;
  unsigned int u = v.u;
  u += 0x7FFFu + ((u >> 16) & 1u);
  return (unsigned short)(u >> 16);
}
__device__ __forceinline__ float bf2f(unsigned short h) {
  union { unsigned int u; float f; } v; v.u = ((unsigned int)h) << 16;
  return v.f;
}
__device__ __forceinline__ void split3(float x, unsigned short& h, unsigned short& m, unsigned short& l) {
  h = f2bf(x);
  float r1 = x - bf2f(h);
  m = f2bf(r1);
  l = f2bf(r1 - bf2f(m));
}

struct GP {
  const unsigned short *Ah, *Am, *Al;    // A planes [rows,1024] bf16
  const unsigned short *A2h, *A2m, *A2l; // MODE1: tanh(mem) planes for g2 columns
  const float* Ax;         // MODE1 x-role: x_t fp32
  long long strideAx;
  const unsigned int* Whm; // weight (hi<<16)|mid plane [Nrows,1024]
  const unsigned short* Wlo;
  const float* bias;       // per-output-col bias
  const float* xbias;      // x-role bias [4096]
  float* o0; float* o1; float* o2; float* o3;
  float* xkv;              // x-role output [64,4096] fp32
  const float* rf;
  const float* g1; const float* g2;
  float* memf;
  unsigned short *oh, *om, *ol;     // split output planes
  unsigned short *o2h, *o2m, *o2l;  // MODE4: tanh(mem) planes
};

// MODES: 1 = QKV+g2 (+fused x-proj role), 2 = Wo+residual, 3 = Wm1+relu, 4 = Wm2+gates->mem
template<int MODE>
__global__ __launch_bounds__(256) void gemm_k(GP p) {
  const int bn = blockIdx.x, bm = blockIdx.y;
  const bool xrole = (MODE == 1) && (bm == 8);
  if (MODE == 1 && xrole && bn >= 64) return;

  const int tid = threadIdx.x;
  const int lane = tid & 63;
  const int wave = tid >> 6;
  const int wm = (wave >> 1) << 5;
  const int wn = (wave & 1) << 5;
  const int rowA0 = (xrole ? 0 : bm) << 6;

  int wrow0;
  if (MODE == 1 && xrole) wrow0 = (bn < 32) ? (1024 + (bn << 6)) : (5120 + ((bn - 32) << 6));
  else wrow0 = bn << 6;

  const unsigned short* Ah = p.Ah;
  const unsigned short* Am = p.Am;
  const unsigned short* Al = p.Al;
  if (MODE == 1 && !xrole && bn >= 48) { Ah = p.A2h; Am = p.A2m; Al = p.A2l; }

  __shared__ __align__(16) unsigned short lAh[4096];
  __shared__ __align__(16) unsigned short lAm[4096];
  __shared__ __align__(16) unsigned short lAl[4096];
  __shared__ __align__(16) unsigned short lBh[4096];
  __shared__ __align__(16) unsigned short lBm[4096];
  __shared__ __align__(16) unsigned short lBl[4096];

  f4v acc[2][2];
#pragma unroll
  for (int i = 0; i < 2; ++i)
#pragma unroll
    for (int j = 0; j < 2; ++j)
#pragma unroll
      for (int r = 0; r < 4; ++r) acc[i][j][r] = 0.f;

  const int sr = tid >> 3;   // 0..31
  const int sc = tid & 7;    // 16B chunk

  for (int kt = 0; kt < 16; ++kt) {
    const int kcol = (kt << 6) + (sc << 3);
#pragma unroll
    for (int h = 0; h < 2; ++h) {
      const int r = sr + (h << 5);
      const int pos = (r << 6) + ((sc ^ (r & 7)) << 3);
      // ---- A ----
      if (MODE == 1 && xrole) {
        const float4* fp = reinterpret_cast<const float4*>(p.Ax + (size_t)r * p.strideAx + kcol);
        float4 f0 = fp[0], f1 = fp[1];
        float fv[8] = { f0.x, f0.y, f0.z, f0.w, f1.x, f1.y, f1.z, f1.w };
        s8v ah, am, al;
#pragma unroll
        for (int e = 0; e < 8; ++e) {
          unsigned short hb, mb, lb;
          split3(fv[e], hb, mb, lb);
          ah[e] = (short)hb; am[e] = (short)mb; al[e] = (short)lb;
        }
        *reinterpret_cast<s8v*>(&lAh[pos]) = ah;
        *reinterpret_cast<s8v*>(&lAm[pos]) = am;
        *reinterpret_cast<s8v*>(&lAl[pos]) = al;
      } else {
        const size_t ao = (size_t)(rowA0 + r) * 1024 + kcol;
        *reinterpret_cast<s8v*>(&lAh[pos]) = *reinterpret_cast<const s8v*>(Ah + ao);
        *reinterpret_cast<s8v*>(&lAm[pos]) = *reinterpret_cast<const s8v*>(Am + ao);
        *reinterpret_cast<s8v*>(&lAl[pos]) = *reinterpret_cast<const s8v*>(Al + ao);
      }
      // ---- B ----
      const uint4* up = reinterpret_cast<const uint4*>(p.Whm + (size_t)(wrow0 + r) * 1024 + kcol);
      uint4 u0 = up[0], u1 = up[1];
      s8v bh, bm_;
      bh[0] = (short)(u0.x >> 16); bm_[0] = (short)(u0.x & 0xFFFFu);
      bh[1] = (short)(u0.y >> 16); bm_[1] = (short)(u0.y & 0xFFFFu);
      bh[2] = (short)(u0.z >> 16); bm_[2] = (short)(u0.z & 0xFFFFu);
      bh[3] = (short)(u0.w >> 16); bm_[3] = (short)(u0.w & 0xFFFFu);
      bh[4] = (short)(u1.x >> 16); bm_[4] = (short)(u1.x & 0xFFFFu);
      bh[5] = (short)(u1.y >> 16); bm_[5] = (short)(u1.y & 0xFFFFu);
      bh[6] = (short)(u1.z >> 16); bm_[6] = (short)(u1.z & 0xFFFFu);
      bh[7] = (short)(u1.w >> 16); bm_[7] = (short)(u1.w & 0xFFFFu);
      s8v bl = *reinterpret_cast<const s8v*>(p.Wlo + (size_t)(wrow0 + r) * 1024 + kcol);
      *reinterpret_cast<s8v*>(&lBh[pos]) = bh;
      *reinterpret_cast<s8v*>(&lBm[pos]) = bm_;
      *reinterpret_cast<s8v*>(&lBl[pos]) = bl;
    }
    __syncthreads();
#pragma unroll
    for (int ks = 0; ks < 2; ++ks) {
      s8v afh[2], afm[2], afl[2], bfh[2], bfm[2], bfl[2];
#pragma unroll
      for (int i = 0; i < 2; ++i) {
        const int rr = wm + (i << 4) + (lane & 15);
        const int cc = (ks << 2) + (lane >> 4);
        const int pos = (rr << 6) + ((cc ^ (rr & 7)) << 3);
        afh[i] = *reinterpret_cast<const s8v*>(&lAh[pos]);
        afm[i] = *reinterpret_cast<const s8v*>(&lAm[pos]);
        afl[i] = *reinterpret_cast<const s8v*>(&lAl[pos]);
      }
#pragma unroll
      for (int j = 0; j < 2; ++j) {
        const int rr = wn + (j << 4) + (lane & 15);
        const int cc = (ks << 2) + (lane >> 4);
        const int pos = (rr << 6) + ((cc ^ (rr & 7)) << 3);
        bfh[j] = *reinterpret_cast<const s8v*>(&lBh[pos]);
        bfm[j] = *reinterpret_cast<const s8v*>(&lBm[pos]);
        bfl[j] = *reinterpret_cast<const s8v*>(&lBl[pos]);
      }
#pragma unroll
      for (int i = 0; i < 2; ++i)
#pragma unroll
        for (int j = 0; j < 2; ++j) {
          // 6-product split-3, small-to-large (dropped: ml, lm, ll ~ <=2^-26 rel)
          acc[i][j] = __builtin_amdgcn_mfma_f32_16x16x32_bf16(afl[i], bfh[j], acc[i][j], 0, 0, 0);
          acc[i][j] = __builtin_amdgcn_mfma_f32_16x16x32_bf16(afh[i], bfl[j], acc[i][j], 0, 0, 0);
          acc[i][j] = __builtin_amdgcn_mfma_f32_16x16x32_bf16(afm[i], bfm[j], acc[i][j], 0, 0, 0);
          acc[i][j] = __builtin_amdgcn_mfma_f32_16x16x32_bf16(afm[i], bfh[j], acc[i][j], 0, 0, 0);
          acc[i][j] = __builtin_amdgcn_mfma_f32_16x16x32_bf16(afh[i], bfm[j], acc[i][j], 0, 0, 0);
          acc[i][j] = __builtin_amdgcn_mfma_f32_16x16x32_bf16(afh[i], bfh[j], acc[i][j], 0, 0, 0);
        }
    }
    __syncthreads();
  }

#pragma unroll
  for (int i = 0; i < 2; ++i) {
#pragma unroll
    for (int j = 0; j < 2; ++j) {
      const int lcol = wn + (j << 4) + (lane & 15);
#pragma unroll
      for (int rg = 0; rg < 4; ++rg) {
        const int grow = rowA0 + wm + (i << 4) + ((lane >> 4) << 2) + rg;
        float v = acc[i][j][rg];
        if (MODE == 1) {
          if (xrole) {
            const int gcol = (bn < 32) ? ((bn << 6) + lcol) : (2048 + ((bn - 32) << 6) + lcol);
            p.xkv[(size_t)grow * 4096 + gcol] = v + p.xbias[gcol];
          } else {
            const int gcol5 = (bn << 6) + lcol;
            float val = v + p.bias[gcol5];
            if (gcol5 < 1024)      p.o0[(size_t)grow * 1024 + gcol5] = val;
            else if (gcol5 < 2048) p.o1[(size_t)grow * 1024 + gcol5 - 1024] = val;
            else if (gcol5 < 3072) p.o2[(size_t)grow * 1024 + gcol5 - 2048] = val;
            else                   p.o3[(size_t)grow * 2048 + gcol5 - 3072] = val;
          }
        } else {
          const int gcol = (bn << 6) + lcol;
          const size_t idx = (size_t)grow * 1024 + gcol;
          if (MODE == 2) {
            float na = v + p.bias[gcol] + p.rf[idx];
            p.o0[idx] = na;
            unsigned short hb, mb, lb;
            split3(na, hb, mb, lb);
            p.oh[idx] = hb; p.om[idx] = mb; p.ol[idx] = lb;
          } else if (MODE == 3) {
            float hh = v + p.bias[gcol];
            hh = hh > 0.f ? hh : 0.f;
            unsigned short hb, mb, lb;
            split3(hh, hb, mb, lb);
            p.oh[idx] = hb; p.om[idx] = mb; p.ol[idx] = lb;
          } else if (MODE == 4) {
            float relu = v + p.bias[gcol];
            relu = relu > 0.f ? relu : 0.f;
            double nm = (double)p.rf[idx] + (double)relu;
            int b = grow >> 3;
            double gi = (double)p.g1[(size_t)b * 4096 + 2048 + gcol] + (double)p.g2[(size_t)grow * 2048 + gcol];
            double gf = (double)p.g1[(size_t)b * 4096 + 3072 + gcol] + (double)p.g2[(size_t)grow * 2048 + 1024 + gcol];
            double ig = 1.0 / (1.0 + exp(-gi));
            double fg = 1.0 / (1.0 + exp(-gf));
            double nxt = ig * tanh(nm) + fg * (double)p.memf[idx];
            float nf = (float)nxt;
            float tf = (float)tanh(nxt);
            p.memf[idx] = nf;
            unsigned short hb, mb, lb;
            split3(nf, hb, mb, lb);
            p.oh[idx] = hb; p.om[idx] = mb; p.ol[idx] = lb;
            split3(tf, hb, mb, lb);
            p.o2h[idx] = hb; p.o2m[idx] = mb; p.o2l[idx] = lb;
          }
        }
      }
    }
  }
}

__global__ __launch_bounds__(128) void attn_k(const float* q, const float* km, const float* vm,
                                              const float* xkv,
                                              unsigned short* ah, unsigned short* am,
                                              unsigned short* al) {
  const int b = blockIdx.x >> 3;
  const int h = blockIdx.x & 7;
  const int tid = threadIdx.x;
  __shared__ float sq[8][132];
  __shared__ float sk[9][132];
  __shared__ float sv[9][132];
  __shared__ double sc_[8][12];
  __shared__ double sp[8][12];

  for (int i = tid; i < 8 * 128; i += 128) {
    int s = i >> 7, d = i & 127;
    sq[s][d] = q[(size_t)(b * 8 + s) * 1024 + h * 128 + d];
  }
  for (int i = tid; i < 9 * 128; i += 128) {
    int s = i >> 7, d = i & 127;
    float kv, vv;
    if (s < 8) {
      kv = km[(size_t)(b * 8 + s) * 1024 + h * 128 + d];
      vv = vm[(size_t)(b * 8 + s) * 1024 + h * 128 + d];
    } else {
      kv = xkv[(size_t)b * 4096 + h * 128 + d];
      vv = xkv[(size_t)b * 4096 + 1024 + h * 128 + d];
    }
    sk[s][d] = kv; sv[s][d] = vv;
  }
  __syncthreads();
  if (tid < 72) {
    int s = tid / 9, kk = tid % 9;
    double a = 0.0;
    for (int d = 0; d < 128; ++d) a += (double)sq[s][d] * (double)sk[kk][d];
    sc_[s][kk] = a * 0.08838834764831844055;  // 1/sqrt(128)
  }
  __syncthreads();
  if (tid < 8) {
    double m = -1e300;
    for (int kk = 0; kk < 9; ++kk) m = m > sc_[tid][kk] ? m : sc_[tid][kk];
    double sum = 0.0;
    for (int kk = 0; kk < 9; ++kk) { double e = exp(sc_[tid][kk] - m); sp[tid][kk] = e; sum += e; }
    double inv = 1.0 / sum;
    for (int kk = 0; kk < 9; ++kk) sp[tid][kk] *= inv;
  }
  __syncthreads();
  for (int i = tid; i < 8 * 128; i += 128) {
    int s = i >> 7, d = i & 127;
    double a = 0.0;
    for (int kk = 0; kk < 9; ++kk) a += sp[s][kk] * (double)sv[kk][d];
    size_t idx = (size_t)(b * 8 + s) * 1024 + h * 128 + d;
    unsigned short hb, mb, lb;
    split3((float)a, hb, mb, lb);
    ah[idx] = hb; am[idx] = mb; al[idx] = lb;
  }
}

// src fp32 [K=1024 rows, N cols] -> dst_hm (hi<<16|mid) [N,1024], dst_lo [N,1024]
__global__ __launch_bounds__(256) void wtp_k(const float* src, unsigned int* dst_hm,
                                             unsigned short* dst_lo, int N) {
  __shared__ float tile[32][33];
  const int bn = blockIdx.x << 5;
  const int bk = blockIdx.y << 5;
  const int tid = threadIdx.x;
  for (int i = tid; i < 1024; i += 256) {
    int r = i >> 5, c = i & 31;
    tile[r][c] = src[(size_t)(bk + r) * N + bn + c];
  }
  __syncthreads();
  for (int i = tid; i < 1024; i += 256) {
    int r = i >> 5, c = i & 31;
    float v = tile[c][r];
    unsigned short hb, mb, lb;
    split3(v, hb, mb, lb);
    size_t o = (size_t)(bn + r) * 1024 + bk + c;
    dst_hm[o] = ((unsigned int)hb << 16) | (unsigned int)mb;
    dst_lo[o] = lb;
  }
}

__global__ __launch_bounds__(256) void biasp_k(const float* bq, const float* bk, const float* bv,
                                               const float* bw, const float* bu,
                                               float* bias1, float* xbias) {
  int i = blockIdx.x * 256 + threadIdx.x;  // 0..9215
  if (i < 5120) {
    float v;
    if (i < 1024) v = bq[i];
    else if (i < 2048) v = bk[i - 1024];
    else if (i < 3072) v = bv[i - 2048];
    else v = 0.f;
    bias1[i] = v;
  } else {
    int j = i - 5120;  // 0..4095
    float v;
    if (j < 1024) v = bk[j];
    else if (j < 2048) v = bv[j - 1024];
    else v = bw[j - 2048] + bu[j - 2048];
    xbias[j] = v;
  }
}

__global__ __launch_bounds__(256) void init_k(const float* memory, float* memF,
                                              unsigned short* mh, unsigned short* mm, unsigned short* ml,
                                              unsigned short* th, unsigned short* tm, unsigned short* tl) {
  int i = blockIdx.x * 256 + threadIdx.x;
  float v = memory[i];
  memF[i] = v;
  unsigned short hb, mb, lb;
  split3(v, hb, mb, lb);
  mh[i] = hb; mm[i] = mb; ml[i] = lb;
  float t = (float)tanh((double)v);
  split3(t, hb, mb, lb);
  th[i] = hb; tm[i] = mb; tl[i] = lb;
}

extern "C" void kernel_launch(void* const* d_in, const int* in_sizes, int n_in,
                              void* d_out, int out_size, void* d_ws, size_t ws_size,
                              hipStream_t stream) {
  const float* inputs = (const float*)d_in[0];
  const float* memory = (const float*)d_in[1];
  const float* Wq = (const float*)d_in[2];  const float* bq = (const float*)d_in[3];
  const float* Wk = (const float*)d_in[4];  const float* bk = (const float*)d_in[5];
  const float* Wv = (const float*)d_in[6];  const float* bv = (const float*)d_in[7];
  const float* Wo = (const float*)d_in[8];  const float* bo = (const float*)d_in[9];
  const float* Wm1 = (const float*)d_in[10]; const float* bm1 = (const float*)d_in[11];
  const float* Wm2 = (const float*)d_in[12]; const float* bm2 = (const float*)d_in[13];
  const float* Ww = (const float*)d_in[14]; const float* bw = (const float*)d_in[15];
  const float* Wu = (const float*)d_in[16]; const float* bu = (const float*)d_in[17];
  (void)in_sizes; (void)n_in; (void)out_size; (void)ws_size;

  char* ws = (char*)d_ws;
  const size_t MB = 1024 * 1024;
  // weight concat rows: [Wq 0..1023 | Wk 1024..2047 | Wv 2048..3071 | Wu 3072..5119 | Ww 5120..7167]
  unsigned int*   cat_hm = (unsigned int*)(ws + 0 * MB);    // 28MB
  unsigned short* cat_lo = (unsigned short*)(ws + 28 * MB); // 14MB
  unsigned int*   wo_hm  = (unsigned int*)(ws + 42 * MB);
  unsigned short* wo_lo  = (unsigned short*)(ws + 46 * MB);
  unsigned int*   wm1_hm = (unsigned int*)(ws + 48 * MB);
  unsigned short* wm1_lo = (unsigned short*)(ws + 52 * MB);
  unsigned int*   wm2_hm = (unsigned int*)(ws + 54 * MB);
  unsigned short* wm2_lo = (unsigned short*)(ws + 58 * MB);
  float* bias1 = (float*)(ws + 60 * MB);            // [5120]
  float* xbias = (float*)(ws + 60 * MB + 64 * 1024); // [4096]
  float* memF  = (float*)(ws + 61 * MB);  // [512,1024] fp32
  float* qF    = (float*)(ws + 63 * MB);
  float* kmemF = (float*)(ws + 65 * MB);
  float* vmemF = (float*)(ws + 67 * MB);
  float* g2F   = (float*)(ws + 69 * MB);  // [512,2048]
  float* naF   = (float*)(ws + 73 * MB);
  float* xkvF  = (float*)(ws + 75 * MB);  // [64,4096]
  unsigned short* memH  = (unsigned short*)(ws + 76 * MB);
  unsigned short* memM  = (unsigned short*)(ws + 77 * MB);
  unsigned short* memL  = (unsigned short*)(ws + 78 * MB);
  unsigned short* tmemH = (unsigned short*)(ws + 79 * MB);
  unsigned short* tmemM = (unsigned short*)(ws + 80 * MB);
  unsigned short* tmemL = (unsigned short*)(ws + 81 * MB);
  unsigned short* attnH = (unsigned short*)(ws + 82 * MB);
  unsigned short* attnM = (unsigned short*)(ws + 83 * MB);
  unsigned short* attnL = (unsigned short*)(ws + 84 * MB);
  unsigned short* naH   = (unsigned short*)(ws + 85 * MB);
  unsigned short* naM   = (unsigned short*)(ws + 86 * MB);
  unsigned short* naL   = (unsigned short*)(ws + 87 * MB);
  unsigned short* hidH  = (unsigned short*)(ws + 88 * MB);
  unsigned short* hidM  = (unsigned short*)(ws + 89 * MB);
  unsigned short* hidL  = (unsigned short*)(ws + 90 * MB);

  wtp_k<<<dim3(32, 32), 256, 0, stream>>>(Wq, cat_hm, cat_lo, 1024);
  wtp_k<<<dim3(32, 32), 256, 0, stream>>>(Wk, cat_hm + (size_t)1024 * 1024, cat_lo + (size_t)1024 * 1024, 1024);
  wtp_k<<<dim3(32, 32), 256, 0, stream>>>(Wv, cat_hm + (size_t)2048 * 1024, cat_lo + (size_t)2048 * 1024, 1024);
  wtp_k<<<dim3(64, 32), 256, 0, stream>>>(Wu, cat_hm + (size_t)3072 * 1024, cat_lo + (size_t)3072 * 1024, 2048);
  wtp_k<<<dim3(64, 32), 256, 0, stream>>>(Ww, cat_hm + (size_t)5120 * 1024, cat_lo + (size_t)5120 * 1024, 2048);
  wtp_k<<<dim3(32, 32), 256, 0, stream>>>(Wo, wo_hm, wo_lo, 1024);
  wtp_k<<<dim3(32, 32), 256, 0, stream>>>(Wm1, wm1_hm, wm1_lo, 1024);
  wtp_k<<<dim3(32, 32), 256, 0, stream>>>(Wm2, wm2_hm, wm2_lo, 1024);
  biasp_k<<<dim3(36), 256, 0, stream>>>(bq, bk, bv, bw, bu, bias1, xbias);
  init_k<<<dim3(512 * 1024 / 256), 256, 0, stream>>>(memory, memF, memH, memM, memL, tmemH, tmemM, tmemL);

  for (int t = 0; t < TT; ++t) {
    { // fused: Q|K|V|g2 projection (bm 0..7) + x-projections (bm==8)
      GP p = {};
      p.Ah = memH; p.Am = memM; p.Al = memL;
      p.A2h = tmemH; p.A2m = tmemM; p.A2l = tmemL;
      p.Ax = inputs + (size_t)t * 1024; p.strideAx = (long long)TT * 1024;
      p.Whm = cat_hm; p.Wlo = cat_lo;
      p.bias = bias1; p.xbias = xbias;
      p.o0 = qF; p.o1 = kmemF; p.o2 = vmemF; p.o3 = g2F; p.xkv = xkvF;
      gemm_k<1><<<dim3(80, 9), 256, 0, stream>>>(p);
    }
    attn_k<<<dim3(512), 128, 0, stream>>>(qF, kmemF, vmemF, xkvF, attnH, attnM, attnL);
    { // attn @ Wo + bo + mem -> naF + na planes
      GP p = {};
      p.Ah = attnH; p.Am = attnM; p.Al = attnL;
      p.Whm = wo_hm; p.Wlo = wo_lo; p.bias = bo; p.rf = memF;
      p.o0 = naF; p.oh = naH; p.om = naM; p.ol = naL;
      gemm_k<2><<<dim3(16, 8), 256, 0, stream>>>(p);
    }
    { // relu(na @ Wm1 + bm1) -> hid planes
      GP p = {};
      p.Ah = naH; p.Am = naM; p.Al = naL;
      p.Whm = wm1_hm; p.Wlo = wm1_lo; p.bias = bm1;
      p.oh = hidH; p.om = hidM; p.ol = hidL;
      gemm_k<3><<<dim3(16, 8), 256, 0, stream>>>(p);
    }
    { // hid @ Wm2 + gates -> mem update
      GP p = {};
      p.Ah = hidH; p.Am = hidM; p.Al = hidL;
      p.Whm = wm2_hm; p.Wlo = wm2_lo; p.bias = bm2; p.rf = naF;
      p.g1 = xkvF; p.g2 = g2F; p.memf = memF;
      p.oh = memH; p.om = memM; p.ol = memL;
      p.o2h = tmemH; p.o2m = tmemM; p.o2l = tmemL;
      gemm_k<4><<<dim3(16, 8), 256, 0, stream>>>(p);
    }
  }

  hipMemcpyAsync(d_out, memF, (size_t)512 * 1024 * 4, hipMemcpyDeviceToDevice, stream);
}

// Round 6
// 15386.711 us; speedup vs baseline: 1.9996x; 1.6776x over previous
//
#include <hip/hip_runtime.h>
#include <math.h>

#define TT 128

typedef __attribute__((ext_vector_type(8))) short s8v;
typedef __attribute__((ext_vector_type(4))) float f4v;

__device__ __forceinline__ unsigned short f2bf(float f) {
  union { float f; unsigned int u; } v; v.f = f;
  unsigned int u = v.u;
  u += 0x7FFFu + ((u >> 16) & 1u);
  return (unsigned short)(u >> 16);
}
__device__ __forceinline__ float bf2f(unsigned short h) {
  union { unsigned int u; float f; } v; v.u = ((unsigned int)h) << 16;
  return v.f;
}
__device__ __forceinline__ void split3(float x, unsigned short& h, unsigned short& m, unsigned short& l) {
  h = f2bf(x);
  float r1 = x - bf2f(h);
  m = f2bf(r1);
  l = f2bf(r1 - bf2f(m));
}
__device__ __forceinline__ void gload16(const void* g, void* l) {
  __builtin_amdgcn_global_load_lds(
      (const __attribute__((address_space(1))) void*)g,
      (__attribute__((address_space(3))) void*)l, 16, 0, 0);
}

struct GP {
  const unsigned short *Ah, *Am, *Al;    // A planes [rows,1024]
  const unsigned short *A2h, *A2m, *A2l; // MODE1: tanh(mem) planes
  const float* Ax;          // MODE1 x-role: x_t fp32
  long long strideAx;
  const unsigned short *Bh, *Bm, *Bl;    // weight planes [Nrows,1024]
  const float* bias;
  const float* xbias;
  float* o0;                // qkvg (MODE1) / naF (MODE2)
  float* xkv;               // [64,4096]
  const float* rf; const float* g1; const float* g2;
  float* memf;
  unsigned short *oh, *om, *ol;
  unsigned short *o2h, *o2m, *o2l;
};

// MODE 1: QKV|g2 from mem/tanh(mem) + fused x-proj (bm==8). out qkvg [512,5120]
// MODE 2: attn@Wo + bo + mem -> naF + planes.  MODE 3: relu(na@Wm1+bm1) -> hid planes.
// MODE 4: hid@Wm2 + gates -> mem update.
template<int MODE>
__global__ __launch_bounds__(256) void gemm_k(GP p) {
  constexpr int BM = (MODE == 1) ? 64 : 32;
  constexpr int MI = BM / 32;
  const int bn = blockIdx.x, bm = blockIdx.y;
  const bool xrole = (MODE == 1) && (bm == 8);
  if (MODE == 1 && xrole && bn >= 64) return;

  const int tid = threadIdx.x;
  const int lane = tid & 63;
  const int wave = tid >> 6;
  const int wm = (wave >> 1) * (16 * MI);
  const int wn = (wave & 1) << 5;
  const int rowA0 = (xrole ? 0 : bm) * BM;

  int wrow0;
  if (MODE == 1 && xrole) wrow0 = (bn < 32) ? (1024 + (bn << 6)) : (5120 + ((bn - 32) << 6));
  else wrow0 = bn << 6;

  const unsigned short* Ah = p.Ah;
  const unsigned short* Am = p.Am;
  const unsigned short* Al = p.Al;
  if (MODE == 1 && !xrole && bn >= 48) { Ah = p.A2h; Am = p.A2m; Al = p.A2l; }

  __shared__ __align__(16) unsigned short lAh[BM * 64];
  __shared__ __align__(16) unsigned short lAm[BM * 64];
  __shared__ __align__(16) unsigned short lAl[BM * 64];
  __shared__ __align__(16) unsigned short lBh[64 * 64];
  __shared__ __align__(16) unsigned short lBm[64 * 64];
  __shared__ __align__(16) unsigned short lBl[64 * 64];

  f4v acc[MI][2];
#pragma unroll
  for (int i = 0; i < MI; ++i)
#pragma unroll
    for (int j = 0; j < 2; ++j)
#pragma unroll
      for (int r = 0; r < 4; ++r) acc[i][j][r] = 0.f;

  const int lr = lane >> 3, lc = lane & 7;

  for (int kt = 0; kt < 16; ++kt) {
    const int kcol = kt << 6;
    // ---- A staging ----
    if (!xrole) {
#pragma unroll
      for (int rep = 0; rep < MI; ++rep) {
        const int rbase = (wave << 3) + (rep << 5);
        const int r = rbase + lr;
        const size_t so = (size_t)(rowA0 + r) * 1024 + kcol + ((lc ^ (r & 7)) << 3);
        gload16(Ah + so, &lAh[rbase << 6]);
        gload16(Am + so, &lAm[rbase << 6]);
        gload16(Al + so, &lAl[rbase << 6]);
      }
    } else {
      // x_t fp32 -> split-3 on the fly (only 64 blocks total)
#pragma unroll
      for (int h = 0; h < 2; ++h) {
        const int r = (tid >> 3) + (h << 5);
        const int sc = tid & 7;
        const float4* fp = reinterpret_cast<const float4*>(p.Ax + (size_t)r * p.strideAx + kcol + (sc << 3));
        float4 f0 = fp[0], f1 = fp[1];
        float fv[8] = { f0.x, f0.y, f0.z, f0.w, f1.x, f1.y, f1.z, f1.w };
        s8v ah, am, al;
#pragma unroll
        for (int e = 0; e < 8; ++e) {
          unsigned short hb, mb, lb;
          split3(fv[e], hb, mb, lb);
          ah[e] = (short)hb; am[e] = (short)mb; al[e] = (short)lb;
        }
        const int pos = (r << 6) + ((sc ^ (r & 7)) << 3);
        *reinterpret_cast<s8v*>(&lAh[pos]) = ah;
        *reinterpret_cast<s8v*>(&lAm[pos]) = am;
        *reinterpret_cast<s8v*>(&lAl[pos]) = al;
      }
    }
    // ---- B staging (always 64 rows) ----
#pragma unroll
    for (int rep = 0; rep < 2; ++rep) {
      const int rbase = (wave << 3) + (rep << 5);
      const int r = rbase + lr;
      const size_t so = (size_t)(wrow0 + r) * 1024 + kcol + ((lc ^ (r & 7)) << 3);
      gload16(p.Bh + so, &lBh[rbase << 6]);
      gload16(p.Bm + so, &lBm[rbase << 6]);
      gload16(p.Bl + so, &lBl[rbase << 6]);
    }
    __syncthreads();
#pragma unroll
    for (int ks = 0; ks < 2; ++ks) {
      s8v afh[MI], afm[MI], afl[MI], bfh[2], bfm[2], bfl[2];
#pragma unroll
      for (int i = 0; i < MI; ++i) {
        const int rr = wm + (i << 4) + (lane & 15);
        const int cc = (ks << 2) + (lane >> 4);
        const int pos = (rr << 6) + ((cc ^ (rr & 7)) << 3);
        afh[i] = *reinterpret_cast<const s8v*>(&lAh[pos]);
        afm[i] = *reinterpret_cast<const s8v*>(&lAm[pos]);
        afl[i] = *reinterpret_cast<const s8v*>(&lAl[pos]);
      }
#pragma unroll
      for (int j = 0; j < 2; ++j) {
        const int rr = wn + (j << 4) + (lane & 15);
        const int cc = (ks << 2) + (lane >> 4);
        const int pos = (rr << 6) + ((cc ^ (rr & 7)) << 3);
        bfh[j] = *reinterpret_cast<const s8v*>(&lBh[pos]);
        bfm[j] = *reinterpret_cast<const s8v*>(&lBm[pos]);
        bfl[j] = *reinterpret_cast<const s8v*>(&lBl[pos]);
      }
#pragma unroll
      for (int i = 0; i < MI; ++i)
#pragma unroll
        for (int j = 0; j < 2; ++j) {
          acc[i][j] = __builtin_amdgcn_mfma_f32_16x16x32_bf16(afl[i], bfh[j], acc[i][j], 0, 0, 0);
          acc[i][j] = __builtin_amdgcn_mfma_f32_16x16x32_bf16(afh[i], bfl[j], acc[i][j], 0, 0, 0);
          acc[i][j] = __builtin_amdgcn_mfma_f32_16x16x32_bf16(afm[i], bfm[j], acc[i][j], 0, 0, 0);
          acc[i][j] = __builtin_amdgcn_mfma_f32_16x16x32_bf16(afm[i], bfh[j], acc[i][j], 0, 0, 0);
          acc[i][j] = __builtin_amdgcn_mfma_f32_16x16x32_bf16(afh[i], bfm[j], acc[i][j], 0, 0, 0);
          acc[i][j] = __builtin_amdgcn_mfma_f32_16x16x32_bf16(afh[i], bfh[j], acc[i][j], 0, 0, 0);
        }
    }
    __syncthreads();
  }

#pragma unroll
  for (int i = 0; i < MI; ++i) {
#pragma unroll
    for (int j = 0; j < 2; ++j) {
      const int lcol = wn + (j << 4) + (lane & 15);
#pragma unroll
      for (int rg = 0; rg < 4; ++rg) {
        const int grow = rowA0 + wm + (i << 4) + ((lane >> 4) << 2) + rg;
        float v = acc[i][j][rg];
        if (MODE == 1) {
          if (xrole) {
            const int gcol = (bn < 32) ? ((bn << 6) + lcol) : (2048 + ((bn - 32) << 6) + lcol);
            p.xkv[(size_t)grow * 4096 + gcol] = v + p.xbias[gcol];
          } else {
            const int gcol = (bn << 6) + lcol;
            p.o0[(size_t)grow * 5120 + gcol] = v + p.bias[gcol];
          }
        } else {
          const int gcol = (bn << 6) + lcol;
          const size_t idx = (size_t)grow * 1024 + gcol;
          if (MODE == 2) {
            float na = v + p.bias[gcol] + p.rf[idx];
            p.o0[idx] = na;
            unsigned short hb, mb, lb;
            split3(na, hb, mb, lb);
            p.oh[idx] = hb; p.om[idx] = mb; p.ol[idx] = lb;
          } else if (MODE == 3) {
            float hh = v + p.bias[gcol];
            hh = hh > 0.f ? hh : 0.f;
            unsigned short hb, mb, lb;
            split3(hh, hb, mb, lb);
            p.oh[idx] = hb; p.om[idx] = mb; p.ol[idx] = lb;
          } else if (MODE == 4) {
            float relu = v + p.bias[gcol];
            relu = relu > 0.f ? relu : 0.f;
            double nm = (double)p.rf[idx] + (double)relu;
            int b = grow >> 3;
            double gi = (double)p.g1[(size_t)b * 4096 + 2048 + gcol] + (double)p.g2[(size_t)grow * 5120 + 3072 + gcol];
            double gf = (double)p.g1[(size_t)b * 4096 + 3072 + gcol] + (double)p.g2[(size_t)grow * 5120 + 4096 + gcol];
            double ig = 1.0 / (1.0 + exp(-gi));
            double fg = 1.0 / (1.0 + exp(-gf));
            double nxt = ig * tanh(nm) + fg * (double)p.memf[idx];
            float nf = (float)nxt;
            float tf = (float)tanh(nxt);
            p.memf[idx] = nf;
            unsigned short hb, mb, lb;
            split3(nf, hb, mb, lb);
            p.oh[idx] = hb; p.om[idx] = mb; p.ol[idx] = lb;
            split3(tf, hb, mb, lb);
            p.o2h[idx] = hb; p.o2m[idx] = mb; p.o2l[idx] = lb;
          }
        }
      }
    }
  }
}

__global__ __launch_bounds__(128) void attn_k(const float* qkvg, const float* xkv,
                                              unsigned short* ah, unsigned short* am,
                                              unsigned short* al) {
  const int b = blockIdx.x >> 3;
  const int h = blockIdx.x & 7;
  const int tid = threadIdx.x;
  __shared__ float sq[8][132];
  __shared__ float sk[9][132];
  __shared__ float sv[9][132];
  __shared__ double sc_[8][12];
  __shared__ double sp[8][12];

  for (int i = tid; i < 8 * 128; i += 128) {
    int s = i >> 7, d = i & 127;
    sq[s][d] = qkvg[(size_t)(b * 8 + s) * 5120 + h * 128 + d];
  }
  for (int i = tid; i < 9 * 128; i += 128) {
    int s = i >> 7, d = i & 127;
    float kv, vv;
    if (s < 8) {
      kv = qkvg[(size_t)(b * 8 + s) * 5120 + 1024 + h * 128 + d];
      vv = qkvg[(size_t)(b * 8 + s) * 5120 + 2048 + h * 128 + d];
    } else {
      kv = xkv[(size_t)b * 4096 + h * 128 + d];
      vv = xkv[(size_t)b * 4096 + 1024 + h * 128 + d];
    }
    sk[s][d] = kv; sv[s][d] = vv;
  }
  __syncthreads();
  if (tid < 72) {
    int s = tid / 9, kk = tid % 9;
    double a = 0.0;
    for (int d = 0; d < 128; ++d) a += (double)sq[s][d] * (double)sk[kk][d];
    sc_[s][kk] = a * 0.08838834764831844055;  // 1/sqrt(128)
  }
  __syncthreads();
  if (tid < 8) {
    double m = -1e300;
    for (int kk = 0; kk < 9; ++kk) m = m > sc_[tid][kk] ? m : sc_[tid][kk];
    double sum = 0.0;
    for (int kk = 0; kk < 9; ++kk) { double e = exp(sc_[tid][kk] - m); sp[tid][kk] = e; sum += e; }
    double inv = 1.0 / sum;
    for (int kk = 0; kk < 9; ++kk) sp[tid][kk] *= inv;
  }
  __syncthreads();
  for (int i = tid; i < 8 * 128; i += 128) {
    int s = i >> 7, d = i & 127;
    double a = 0.0;
    for (int kk = 0; kk < 9; ++kk) a += sp[s][kk] * (double)sv[kk][d];
    size_t idx = (size_t)(b * 8 + s) * 1024 + h * 128 + d;
    unsigned short hb, mb, lb;
    split3((float)a, hb, mb, lb);
    ah[idx] = hb; am[idx] = mb; al[idx] = lb;
  }
}

// fp32 [1024 (K) rows, N cols] -> 3 bf16 planes [N,1024]
__global__ __launch_bounds__(256) void wtp3_k(const float* src, unsigned short* dh,
                                              unsigned short* dm, unsigned short* dl, int N) {
  __shared__ float tile[32][33];
  const int bn = blockIdx.x << 5;
  const int bk = blockIdx.y << 5;
  const int tid = threadIdx.x;
  for (int i = tid; i < 1024; i += 256) {
    int r = i >> 5, c = i & 31;
    tile[r][c] = src[(size_t)(bk + r) * N + bn + c];
  }
  __syncthreads();
  for (int i = tid; i < 1024; i += 256) {
    int r = i >> 5, c = i & 31;
    float v = tile[c][r];
    unsigned short hb, mb, lb;
    split3(v, hb, mb, lb);
    size_t o = (size_t)(bn + r) * 1024 + bk + c;
    dh[o] = hb; dm[o] = mb; dl[o] = lb;
  }
}

__global__ __launch_bounds__(256) void biasp_k(const float* bq, const float* bk, const float* bv,
                                               const float* bw, const float* bu,
                                               float* bias1, float* xbias) {
  int i = blockIdx.x * 256 + threadIdx.x;  // 0..9215
  if (i < 5120) {
    float v;
    if (i < 1024) v = bq[i];
    else if (i < 2048) v = bk[i - 1024];
    else if (i < 3072) v = bv[i - 2048];
    else v = 0.f;
    bias1[i] = v;
  } else {
    int j = i - 5120;  // 0..4095
    float v;
    if (j < 1024) v = bk[j];
    else if (j < 2048) v = bv[j - 1024];
    else v = bw[j - 2048] + bu[j - 2048];
    xbias[j] = v;
  }
}

__global__ __launch_bounds__(256) void init_k(const float* memory, float* memF,
                                              unsigned short* mh, unsigned short* mm, unsigned short* ml,
                                              unsigned short* th, unsigned short* tm, unsigned short* tl) {
  int i = blockIdx.x * 256 + threadIdx.x;
  float v = memory[i];
  memF[i] = v;
  unsigned short hb, mb, lb;
  split3(v, hb, mb, lb);
  mh[i] = hb; mm[i] = mb; ml[i] = lb;
  float t = (float)tanh((double)v);
  split3(t, hb, mb, lb);
  th[i] = hb; tm[i] = mb; tl[i] = lb;
}

extern "C" void kernel_launch(void* const* d_in, const int* in_sizes, int n_in,
                              void* d_out, int out_size, void* d_ws, size_t ws_size,
                              hipStream_t stream) {
  const float* inputs = (const float*)d_in[0];
  const float* memory = (const float*)d_in[1];
  const float* Wq = (const float*)d_in[2];  const float* bq = (const float*)d_in[3];
  const float* Wk = (const float*)d_in[4];  const float* bk = (const float*)d_in[5];
  const float* Wv = (const float*)d_in[6];  const float* bv = (const float*)d_in[7];
  const float* Wo = (const float*)d_in[8];  const float* bo = (const float*)d_in[9];
  const float* Wm1 = (const float*)d_in[10]; const float* bm1 = (const float*)d_in[11];
  const float* Wm2 = (const float*)d_in[12]; const float* bm2 = (const float*)d_in[13];
  const float* Ww = (const float*)d_in[14]; const float* bw = (const float*)d_in[15];
  const float* Wu = (const float*)d_in[16]; const float* bu = (const float*)d_in[17];
  (void)in_sizes; (void)n_in; (void)out_size; (void)ws_size;

  char* ws = (char*)d_ws;
  const size_t MB = 1024 * 1024;
  // cat rows: [Wq 0..1023 | Wk 1024..2047 | Wv 2048..3071 | Wu 3072..5119 | Ww 5120..7167]
  unsigned short* catH = (unsigned short*)(ws + 0 * MB);   // 14MB each
  unsigned short* catM = (unsigned short*)(ws + 14 * MB);
  unsigned short* catL = (unsigned short*)(ws + 28 * MB);
  unsigned short* woH  = (unsigned short*)(ws + 42 * MB);  // 2MB each
  unsigned short* woM  = (unsigned short*)(ws + 44 * MB);
  unsigned short* woL  = (unsigned short*)(ws + 46 * MB);
  unsigned short* wm1H = (unsigned short*)(ws + 48 * MB);
  unsigned short* wm1M = (unsigned short*)(ws + 50 * MB);
  unsigned short* wm1L = (unsigned short*)(ws + 52 * MB);
  unsigned short* wm2H = (unsigned short*)(ws + 54 * MB);
  unsigned short* wm2M = (unsigned short*)(ws + 56 * MB);
  unsigned short* wm2L = (unsigned short*)(ws + 58 * MB);
  float* bias1 = (float*)(ws + 60 * MB);                  // [5120]
  float* xbias = (float*)(ws + 60 * MB + 64 * 1024);      // [4096]
  float* memF  = (float*)(ws + 61 * MB);                  // [512,1024]
  float* naF   = (float*)(ws + 63 * MB);
  float* qkvg  = (float*)(ws + 65 * MB);                  // [512,5120] 10MB
  float* xkvF  = (float*)(ws + 75 * MB);                  // [64,4096]
  unsigned short* memH  = (unsigned short*)(ws + 76 * MB);
  unsigned short* memM  = (unsigned short*)(ws + 77 * MB);
  unsigned short* memL  = (unsigned short*)(ws + 78 * MB);
  unsigned short* tmemH = (unsigned short*)(ws + 79 * MB);
  unsigned short* tmemM = (unsigned short*)(ws + 80 * MB);
  unsigned short* tmemL = (unsigned short*)(ws + 81 * MB);
  unsigned short* attnH = (unsigned short*)(ws + 82 * MB);
  unsigned short* attnM = (unsigned short*)(ws + 83 * MB);
  unsigned short* attnL = (unsigned short*)(ws + 84 * MB);
  unsigned short* naH   = (unsigned short*)(ws + 85 * MB);
  unsigned short* naM   = (unsigned short*)(ws + 86 * MB);
  unsigned short* naL   = (unsigned short*)(ws + 87 * MB);
  unsigned short* hidH  = (unsigned short*)(ws + 88 * MB);
  unsigned short* hidM  = (unsigned short*)(ws + 89 * MB);
  unsigned short* hidL  = (unsigned short*)(ws + 90 * MB);

  wtp3_k<<<dim3(32, 32), 256, 0, stream>>>(Wq, catH, catM, catL, 1024);
  wtp3_k<<<dim3(32, 32), 256, 0, stream>>>(Wk, catH + (size_t)1024 * 1024, catM + (size_t)1024 * 1024, catL + (size_t)1024 * 1024, 1024);
  wtp3_k<<<dim3(32, 32), 256, 0, stream>>>(Wv, catH + (size_t)2048 * 1024, catM + (size_t)2048 * 1024, catL + (size_t)2048 * 1024, 1024);
  wtp3_k<<<dim3(64, 32), 256, 0, stream>>>(Wu, catH + (size_t)3072 * 1024, catM + (size_t)3072 * 1024, catL + (size_t)3072 * 1024, 2048);
  wtp3_k<<<dim3(64, 32), 256, 0, stream>>>(Ww, catH + (size_t)5120 * 1024, catM + (size_t)5120 * 1024, catL + (size_t)5120 * 1024, 2048);
  wtp3_k<<<dim3(32, 32), 256, 0, stream>>>(Wo, woH, woM, woL, 1024);
  wtp3_k<<<dim3(32, 32), 256, 0, stream>>>(Wm1, wm1H, wm1M, wm1L, 1024);
  wtp3_k<<<dim3(32, 32), 256, 0, stream>>>(Wm2, wm2H, wm2M, wm2L, 1024);
  biasp_k<<<dim3(36), 256, 0, stream>>>(bq, bk, bv, bw, bu, bias1, xbias);
  init_k<<<dim3(512 * 1024 / 256), 256, 0, stream>>>(memory, memF, memH, memM, memL, tmemH, tmemM, tmemL);

  for (int t = 0; t < TT; ++t) {
    { // QKV|g2 + fused x-proj
      GP p = {};
      p.Ah = memH; p.Am = memM; p.Al = memL;
      p.A2h = tmemH; p.A2m = tmemM; p.A2l = tmemL;
      p.Ax = inputs + (size_t)t * 1024; p.strideAx = (long long)TT * 1024;
      p.Bh = catH; p.Bm = catM; p.Bl = catL;
      p.bias = bias1; p.xbias = xbias;
      p.o0 = qkvg; p.xkv = xkvF;
      gemm_k<1><<<dim3(80, 9), 256, 0, stream>>>(p);
    }
    attn_k<<<dim3(512), 128, 0, stream>>>(qkvg, xkvF, attnH, attnM, attnL);
    { // attn @ Wo + bo + mem
      GP p = {};
      p.Ah = attnH; p.Am = attnM; p.Al = attnL;
      p.Bh = woH; p.Bm = woM; p.Bl = woL;
      p.bias = bo; p.rf = memF;
      p.o0 = naF; p.oh = naH; p.om = naM; p.ol = naL;
      gemm_k<2><<<dim3(16, 16), 256, 0, stream>>>(p);
    }
    { // relu(na @ Wm1 + bm1)
      GP p = {};
      p.Ah = naH; p.Am = naM; p.Al = naL;
      p.Bh = wm1H; p.Bm = wm1M; p.Bl = wm1L;
      p.bias = bm1;
      p.oh = hidH; p.om = hidM; p.ol = hidL;
      gemm_k<3><<<dim3(16, 16), 256, 0, stream>>>(p);
    }
    { // hid @ Wm2 + gates -> mem
      GP p = {};
      p.Ah = hidH; p.Am = hidM; p.Al = hidL;
      p.Bh = wm2H; p.Bm = wm2M; p.Bl = wm2L;
      p.bias = bm2; p.rf = naF;
      p.g1 = xkvF; p.g2 = qkvg; p.memf = memF;
      p.oh = memH; p.om = memM; p.ol = memL;
      p.o2h = tmemH; p.o2m = tmemM; p.o2l = tmemL;
      gemm_k<4><<<dim3(16, 16), 256, 0, stream>>>(p);
    }
  }

  hipMemcpyAsync(d_out, memF, (size_t)512 * 1024 * 4, hipMemcpyDeviceToDevice, stream);
}